// Round 6
// baseline (1251.786 us; speedup 1.0000x reference)
//
#include <hip/hip_runtime.h>
#include <hip/hip_bf16.h>
#include <math.h>

// Problem constants
#define TT    2048
#define HH    8
#define RDIM  32
#define BB    2

typedef float  f4 __attribute__((ext_vector_type(4)));
typedef float  f2 __attribute__((ext_vector_type(2)));
typedef int    i4 __attribute__((ext_vector_type(4)));
typedef uint   u2 __attribute__((ext_vector_type(2)));

// round-to-nearest f32 -> bf16 bits (values are positive finite here)
__device__ __forceinline__ uint rnd16(float x) {
    return (__float_as_uint(x) + 0x8000u) >> 16;
}

// readfirstlane for float: MUST bitcast — the builtin is i32, a float arg
// would be value-converted (the R5 bug).
__device__ __forceinline__ float rfl_f32(float x) {
    return __uint_as_float(__builtin_amdgcn_readfirstlane(__float_as_uint(x)));
}

// ---------------------------------------------------------------------------
// Kernel 1: fused projection GEMM.  x[4096][1024] @ (Wq|Wk)[1024][256]
//   sq  [B,T,H,RD] f32  (row-major [4096][256])
//   skT [B,H,RD,T] bf16 (transposed + narrowed for the score kernel)
// BM=64 BN=64 BK=32, 256 thr, acc 4x4. 512 blocks = 2/CU so barriers overlap.
// ---------------------------------------------------------------------------
__global__ __launch_bounds__(256) void proj_gemm(
    const float* __restrict__ x,
    const float* __restrict__ Wq,
    const float* __restrict__ Wk,
    float* __restrict__ sq,
    __hip_bfloat16* __restrict__ skT)
{
    constexpr int BK = 32;
    constexpr int LDA = 68;
    constexpr int LDB = 68;
    __shared__ float As[BK][LDA];   // transposed: As[k][m]
    __shared__ float Bs[BK][LDB];   // Bs[k][n]

    const int m0 = blockIdx.x * 64;
    const int n0 = blockIdx.y * 64;
    const float* W = (n0 < 256) ? Wq : Wk;
    const int nloc = n0 & 255;

    const int tid = threadIdx.x;
    const int tx = tid & 15;            // 16 col groups of 4
    const int ty = tid >> 4;            // 16 row groups of 4

    float acc[4][4] = {};

    for (int k0 = 0; k0 < 1024; k0 += BK) {
        #pragma unroll
        for (int l = 0; l < 2; ++l) {
            int vid = tid + l * 256;
            int row = vid >> 3;         // 0..63
            int cc  = vid & 7;          // k-chunk of 4
            f4 v = *(const f4*)&x[(size_t)(m0 + row) * 1024 + k0 + cc * 4];
            As[cc * 4 + 0][row] = v.x;
            As[cc * 4 + 1][row] = v.y;
            As[cc * 4 + 2][row] = v.z;
            As[cc * 4 + 3][row] = v.w;
        }
        #pragma unroll
        for (int l = 0; l < 2; ++l) {
            int vid = tid + l * 256;
            int kr = vid >> 4;          // 0..31
            int c4 = vid & 15;          // 0..15
            f4 v = *(const f4*)&W[(size_t)(k0 + kr) * 256 + nloc + c4 * 4];
            *(f4*)&Bs[kr][c4 * 4] = v;
        }
        __syncthreads();

        #pragma unroll
        for (int k = 0; k < BK; ++k) {
            const f4 a4 = *(const f4*)&As[k][ty * 4];
            const f4 b4 = *(const f4*)&Bs[k][tx * 4];
            float a[4] = {a4.x, a4.y, a4.z, a4.w};
            float bb[4] = {b4.x, b4.y, b4.z, b4.w};
            #pragma unroll
            for (int r = 0; r < 4; ++r)
                #pragma unroll
                for (int c = 0; c < 4; ++c)
                    acc[r][c] = fmaf(a[r], bb[c], acc[r][c]);
        }
        __syncthreads();
    }

    #pragma unroll
    for (int rr = 0; rr < 4; ++rr) {
        int m = m0 + ty * 4 + rr;
        int b = m >> 11;
        int t = m & 2047;
        #pragma unroll
        for (int cc = 0; cc < 4; ++cc) {
            int n = n0 + tx * 4 + cc;
            float v = acc[rr][cc];
            if (n < 256) {
                sq[(size_t)m * 256 + n] = v;
            } else {
                int nk = n - 256;               // = h*32 + d
                int h = nk >> 5, d = nk & 31;
                skT[(((size_t)(b * HH + h)) * RDIM + d) * TT + t] =
                    __float2bfloat16(v);
            }
        }
    }
}

// ---------------------------------------------------------------------------
// Kernel 2: fused scores + mask + gumbel + softmax.
// One wave handles TWO balanced single rows of one (b,h): row q, then row
// 2047-q, sequentially (registers reused). Per-wave work = nc(q)+nc(2047-q)
// = 9-10 chunk-units for EVERY wave -> no triangle drain.
//  - __launch_bounds__(256,8): VGPR cap 64 -> 8 waves/SIMD for latency hiding
//  - 1 row/wave: packed-exp state is only p[8] (16 VGPRs)
//  - f32x2 packed accumulate -> v_pk_fma_f32 (halves score FMA instructions)
//  - sq row pinned to SGPRs via bitcast readfirstlane
//  - no max pass (logits provably < 26 << 88); exp packed 2x bf16 per uint
//  - no LDS, no barriers; gumbel/out nontemporal (stream-once)
// ---------------------------------------------------------------------------
__global__ __launch_bounds__(256, 8) void score_softmax(
    const float* __restrict__ sq,              // [B*T][256] f32
    const __hip_bfloat16* __restrict__ skT,    // [bh][32][2048] bf16
    const float* __restrict__ gumbel,          // [B,H,T,T] f32
    const int*   __restrict__ mask,            // [H,T,T] int32 bool
    float* __restrict__ out)                   // [B,H,T,T] f32
{
    const int tid  = threadIdx.x;
    const int lane = tid & 63;
    // global wave id, forced uniform (scalar) -> all row state in SGPRs
    const int w  = __builtin_amdgcn_readfirstlane(blockIdx.x * 4 + (tid >> 6));
    const int bh = w & 15;                     // low bits: b=0/1 same-h adjacent
    const int q  = w >> 4;                     // 0..1023
    const int h  = bh & (HH - 1);
    const int b  = bh >> 3;
    const int jb = lane * 4;
    const float RS = 0.17677669529663687f;     // 1/sqrt(RD)

    const ushort* skb = (const ushort*)skT + (size_t)bh * RDIM * TT;

    #pragma unroll 1
    for (int half = 0; half < 2; ++half) {
        const int i  = half ? (2047 - q) : q;  // balanced: nc(q)+nc(2047-q)~9-10
        const int nc = (i >> 8) + 1;           // live 256-col chunks (uniform)

        const float* sqr = sq + ((size_t)(b * TT + i)) * 256 + h * RDIM;
        const float* g0  = gumbel + ((size_t)bh * TT + i) * TT;
        const int*   mp  = mask + ((size_t)h * TT + i) * TT;
        float*       o0  = out + ((size_t)bh * TT + i) * TT;

        // sq row -> SGPRs (bitcast readfirstlane; uniform address)
        float s[RDIM];
        #pragma unroll
        for (int d = 0; d < RDIM; ++d)
            s[d] = rfl_f32(sqr[d]);

        u2 p[8];                               // exp packed 2x bf16 per uint
        float sum = 0.f;

        #pragma unroll
        for (int c = 0; c < 8; ++c) {
            if (c < nc) {
                const int j = c * 256 + jb;
                f4 gv = __builtin_nontemporal_load((const f4*)&g0[j]);
                i4 mv = *(const i4*)&mp[j];

                f2 a01 = {0.f, 0.f}, a23 = {0.f, 0.f};
                #pragma unroll
                for (int d = 0; d < RDIM; ++d) {
                    u2 u = *(const u2*)(skb + (size_t)d * TT + j);
                    f2 v01 = { __uint_as_float(u.x << 16),
                               __uint_as_float(u.x & 0xffff0000u) };
                    f2 v23 = { __uint_as_float(u.y << 16),
                               __uint_as_float(u.y & 0xffff0000u) };
                    f2 sd = { s[d], s[d] };
                    a01 += sd * v01;           // v_pk_fma_f32
                    a23 += sd * v23;
                }
                // logits -> exp directly (dead -> 0); no max pass needed
                float e0 = (j + 0 > i || mv.x) ? 0.f : __expf(fmaf(a01.x, RS, gv.x));
                float e1 = (j + 1 > i || mv.y) ? 0.f : __expf(fmaf(a01.y, RS, gv.y));
                float e2 = (j + 2 > i || mv.z) ? 0.f : __expf(fmaf(a23.x, RS, gv.z));
                float e3 = (j + 3 > i || mv.w) ? 0.f : __expf(fmaf(a23.y, RS, gv.w));

                sum += (e0 + e1) + (e2 + e3);
                p[c].x = (rnd16(e1) << 16) | rnd16(e0);
                p[c].y = (rnd16(e3) << 16) | rnd16(e2);
            }
        }

        // wave-wide row sum (64 lanes)
        #pragma unroll
        for (int sd = 32; sd > 0; sd >>= 1) sum += __shfl_xor(sum, sd);
        const float r = 1.0f / sum;            // > 0 (diagonal always live)

        // store full row; dead chunks write zeros (nontemporal, stream-once)
        #pragma unroll
        for (int c = 0; c < 8; ++c) {
            const int j = c * 256 + jb;
            f4 v;
            if (c < nc) {
                v.x = __uint_as_float(p[c].x << 16) * r;
                v.y = __uint_as_float(p[c].x & 0xffff0000u) * r;
                v.z = __uint_as_float(p[c].y << 16) * r;
                v.w = __uint_as_float(p[c].y & 0xffff0000u) * r;
            } else {
                v = (f4)0.f;
            }
            __builtin_nontemporal_store(v, (f4*)&o0[j]);
        }
    }
}

extern "C" void kernel_launch(void* const* d_in, const int* in_sizes, int n_in,
                              void* d_out, int out_size, void* d_ws, size_t ws_size,
                              hipStream_t stream) {
    const float* x      = (const float*)d_in[0];
    const int*   bmask  = (const int*)d_in[1];   // bool -> int32 per harness
    const float* gumbel = (const float*)d_in[2];
    const float* Wq     = (const float*)d_in[3];
    const float* Wk     = (const float*)d_in[4];
    float* out = (float*)d_out;

    float* sq = (float*)d_ws;                          // 4096*256 f32 = 4 MB
    __hip_bfloat16* skT = (__hip_bfloat16*)(sq + (size_t)4096 * 256);  // 2 MB

    proj_gemm<<<dim3(64, 8), 256, 0, stream>>>(x, Wq, Wk, sq, skT);

    // 16384 waves (16 bh x 1024 balanced row-combos), 4 waves per block
    score_softmax<<<4096, 256, 0, stream>>>(sq, skT, gumbel, bmask, out);
}

// Round 7
// 383.182 us; speedup vs baseline: 3.2668x; 3.2668x over previous
//
#include <hip/hip_runtime.h>
#include <hip/hip_bf16.h>
#include <math.h>

// Problem constants
#define TT    2048
#define HH    8
#define RDIM  32
#define BB    2

typedef float  f4  __attribute__((ext_vector_type(4)));
typedef uint   u2  __attribute__((ext_vector_type(2)));
typedef short  s8v __attribute__((ext_vector_type(8)));   // 8 x bf16 bits (4 VGPR)

// round-to-nearest f32 -> bf16 bits
__device__ __forceinline__ uint rnd16(float x) {
    return (__float_as_uint(x) + 0x8000u) >> 16;
}

// ---------------------------------------------------------------------------
// Kernel 1: fused projection GEMM.  x[4096][1024] @ (Wq|Wk)[1024][256]
// Outputs BOTH projections as bf16 in natural [B,T,H,RD] layout
// ( = [4096][256] bf16 ): sqb (from Wq) and skb (from Wk).
// The score kernel's MFMA fragments read these directly (A: row=lane&15,
// B: col=lane&15 <- sk row t), so no transpose is ever materialized.
// ---------------------------------------------------------------------------
__global__ __launch_bounds__(256) void proj_gemm(
    const float* __restrict__ x,
    const float* __restrict__ Wq,
    const float* __restrict__ Wk,
    ushort* __restrict__ sqb,
    ushort* __restrict__ skb)
{
    constexpr int BK = 32;
    constexpr int LDA = 68;
    constexpr int LDB = 68;
    __shared__ float As[BK][LDA];   // transposed: As[k][m]
    __shared__ float Bs[BK][LDB];   // Bs[k][n]

    const int m0 = blockIdx.x * 64;
    const int n0 = blockIdx.y * 64;
    const float* W = (n0 < 256) ? Wq : Wk;
    const int nloc = n0 & 255;

    const int tid = threadIdx.x;
    const int tx = tid & 15;            // 16 col groups of 4
    const int ty = tid >> 4;            // 16 row groups of 4

    float acc[4][4] = {};

    for (int k0 = 0; k0 < 1024; k0 += BK) {
        #pragma unroll
        for (int l = 0; l < 2; ++l) {
            int vid = tid + l * 256;
            int row = vid >> 3;         // 0..63
            int cc  = vid & 7;          // k-chunk of 4
            f4 v = *(const f4*)&x[(size_t)(m0 + row) * 1024 + k0 + cc * 4];
            As[cc * 4 + 0][row] = v.x;
            As[cc * 4 + 1][row] = v.y;
            As[cc * 4 + 2][row] = v.z;
            As[cc * 4 + 3][row] = v.w;
        }
        #pragma unroll
        for (int l = 0; l < 2; ++l) {
            int vid = tid + l * 256;
            int kr = vid >> 4;          // 0..31
            int c4 = vid & 15;          // 0..15
            f4 v = *(const f4*)&W[(size_t)(k0 + kr) * 256 + nloc + c4 * 4];
            *(f4*)&Bs[kr][c4 * 4] = v;
        }
        __syncthreads();

        #pragma unroll
        for (int k = 0; k < BK; ++k) {
            const f4 a4 = *(const f4*)&As[k][ty * 4];
            const f4 b4 = *(const f4*)&Bs[k][tx * 4];
            float a[4] = {a4.x, a4.y, a4.z, a4.w};
            float bb[4] = {b4.x, b4.y, b4.z, b4.w};
            #pragma unroll
            for (int r = 0; r < 4; ++r)
                #pragma unroll
                for (int c = 0; c < 4; ++c)
                    acc[r][c] = fmaf(a[r], bb[c], acc[r][c]);
        }
        __syncthreads();
    }

    // epilogue: pack 4 consecutive cols as 2 uints of bf16 pairs
    #pragma unroll
    for (int rr = 0; rr < 4; ++rr) {
        int m = m0 + ty * 4 + rr;
        u2 pk;
        pk.x = (rnd16(acc[rr][1]) << 16) | rnd16(acc[rr][0]);
        pk.y = (rnd16(acc[rr][3]) << 16) | rnd16(acc[rr][2]);
        int nn = n0 + tx * 4;
        if (nn < 256) {
            *(u2*)&sqb[(size_t)m * 256 + nn] = pk;
        } else {
            *(u2*)&skb[(size_t)m * 256 + (nn - 256)] = pk;
        }
    }
}

// ---------------------------------------------------------------------------
// Kernel 2: MFMA scores + mask + gumbel + softmax, two-sweep (no P storage).
// One 512-thr block per balanced strip-pair (strips s and 127-s of one bh,
// 16 rows each) -> uniform 129 live 16x16 tiles per block.
// Per strip: sweep 1 = MFMA + exp -> row sums only (values discarded);
// cross-wave LDS reduce -> 1/sum; sweep 2 = recompute (L2-hot re-reads),
// scale, store; zero-fill beyond the causal frontier.
// MFMA fragment layouts (gfx950 16x16x32 bf16):
//   A: row=lane&15, k=(lane>>4)*8+j     B: col=lane&15, k=(lane>>4)*8+j
//   C: col=lane&15, row=(lane>>4)*4+reg (m89-verified)
// ---------------------------------------------------------------------------
__global__ __launch_bounds__(512) void score_mfma(
    const ushort* __restrict__ sqb,     // [4096][256] bf16 bits
    const ushort* __restrict__ skb,     // [4096][256] bf16 bits
    const float*  __restrict__ gumbel,  // [B,H,T,T] f32
    const int*    __restrict__ mask,    // [H,T,T] int32 bool
    float* __restrict__ out)            // [B,H,T,T] f32
{
    const int tid = threadIdx.x;
    const int l   = tid & 63;
    const int w   = __builtin_amdgcn_readfirstlane(tid) >> 6;  // wave id 0..7
    const int bh  = blockIdx.x & 15;
    const int sp  = blockIdx.x >> 4;     // 0..63
    const int h   = bh & (HH - 1);
    const int b   = bh >> 3;
    const int cl  = l & 15;              // tile col / A row
    const int g4  = l >> 4;              // 0..3
    const int rbase = g4 * 4;            // C row base
    const float RS = 0.17677669529663687f;  // 1/sqrt(RD)

    __shared__ float sums_lds[8][16];

    const ushort* sqbase = sqb + ((size_t)b * TT) * 256 + h * RDIM + g4 * 8;
    const ushort* skbase = skb + ((size_t)b * TT) * 256 + h * RDIM + g4 * 8;
    const float*  gb = gumbel + (size_t)bh * TT * TT;
    const int*    mb = mask + (size_t)h * TT * TT;
    float*        ob = out + (size_t)bh * TT * TT;

    #pragma unroll 1
    for (int half = 0; half < 2; ++half) {
        const int s      = half ? (127 - sp) : sp;
        const int i0     = s * 16;
        const int ntiles = s + 1;        // live 16-col tiles (incl. diagonal)
        const int zstart = ntiles * 16;

        // A fragment: 8 consecutive bf16 (one dwordx4)
        s8v afrag = *(const s8v*)(sqbase + (size_t)(i0 + cl) * 256);

        const float* grow = gb + (size_t)(i0 + rbase) * TT;
        const int*   mrow = mb + (size_t)(i0 + rbase) * TT;
        float*       orow = ob + (size_t)(i0 + rbase) * TT;

        // ---- sweep 1: row sums ----
        float sums[4] = {0.f, 0.f, 0.f, 0.f};
        for (int base = 2 * w; base < ntiles; base += 16) {
            #pragma unroll
            for (int u = 0; u < 2; ++u) {
                const int jt = base + u;
                if (jt < ntiles) {
                    const int j = jt * 16 + cl;
                    s8v bfrag = *(const s8v*)(skbase + (size_t)j * 256);
                    f4 z = {0.f, 0.f, 0.f, 0.f};
                    f4 c = __builtin_amdgcn_mfma_f32_16x16x32_bf16(
                               afrag, bfrag, z, 0, 0, 0);
                    #pragma unroll
                    for (int k = 0; k < 4; ++k) {
                        const int i = i0 + rbase + k;
                        float g = grow[(size_t)k * TT + j];
                        int   m = mrow[(size_t)k * TT + j];
                        bool dead = (j > i) || (m != 0);
                        float e = dead ? 0.f : __expf(fmaf(c[k], RS, g));
                        sums[k] += e;
                    }
                }
            }
        }
        // 16-lane (same-row-group) reduce
        #pragma unroll
        for (int k = 0; k < 4; ++k) {
            float v = sums[k];
            v += __shfl_xor(v, 1); v += __shfl_xor(v, 2);
            v += __shfl_xor(v, 4); v += __shfl_xor(v, 8);
            sums[k] = v;
        }
        if (cl == 0) {
            #pragma unroll
            for (int k = 0; k < 4; ++k) sums_lds[w][rbase + k] = sums[k];
        }
        __syncthreads();
        float rinv[4];
        #pragma unroll
        for (int k = 0; k < 4; ++k) {
            float t = 0.f;
            #pragma unroll
            for (int ww = 0; ww < 8; ++ww) t += sums_lds[ww][rbase + k];
            rinv[k] = 1.0f / t;          // diagonal always live -> t > 0
        }
        __syncthreads();                 // LDS reused by next half

        // ---- sweep 2: recompute (L2-hot) + normalize + store ----
        for (int base = 2 * w; base < ntiles; base += 16) {
            #pragma unroll
            for (int u = 0; u < 2; ++u) {
                const int jt = base + u;
                if (jt < ntiles) {
                    const int j = jt * 16 + cl;
                    s8v bfrag = *(const s8v*)(skbase + (size_t)j * 256);
                    f4 z = {0.f, 0.f, 0.f, 0.f};
                    f4 c = __builtin_amdgcn_mfma_f32_16x16x32_bf16(
                               afrag, bfrag, z, 0, 0, 0);
                    #pragma unroll
                    for (int k = 0; k < 4; ++k) {
                        const int i = i0 + rbase + k;
                        float g = grow[(size_t)k * TT + j];
                        int   m = mrow[(size_t)k * TT + j];
                        bool dead = (j > i) || (m != 0);
                        float e = dead ? 0.f : __expf(fmaf(c[k], RS, g));
                        orow[(size_t)k * TT + j] = e * rinv[k];
                    }
                }
            }
        }

        // ---- zero-fill cols beyond the causal frontier ----
        for (int r = 0; r < 16; ++r) {
            for (int cz = zstart + tid * 4; cz < TT; cz += 512 * 4) {
                f4 zz = {0.f, 0.f, 0.f, 0.f};
                *(f4*)&ob[(size_t)(i0 + r) * TT + cz] = zz;
            }
        }
    }
}

extern "C" void kernel_launch(void* const* d_in, const int* in_sizes, int n_in,
                              void* d_out, int out_size, void* d_ws, size_t ws_size,
                              hipStream_t stream) {
    const float* x      = (const float*)d_in[0];
    const int*   bmask  = (const int*)d_in[1];   // bool -> int32 per harness
    const float* gumbel = (const float*)d_in[2];
    const float* Wq     = (const float*)d_in[3];
    const float* Wk     = (const float*)d_in[4];
    float* out = (float*)d_out;

    ushort* sqb = (ushort*)d_ws;                       // 4096*256 bf16 = 2 MB
    ushort* skb = sqb + (size_t)4096 * 256;            // 2 MB

    proj_gemm<<<dim3(64, 8), 256, 0, stream>>>(x, Wq, Wk, sqb, skb);

    // 16 bh x 64 balanced strip-pairs, 512 thr (8 waves) each
    score_mfma<<<1024, 512, 0, stream>>>(sqb, skb, gumbel, bmask, out);
}

// Round 8
// 212.914 us; speedup vs baseline: 5.8793x; 1.7997x over previous
//
#include <hip/hip_runtime.h>
#include <hip/hip_bf16.h>
#include <math.h>

// Problem constants
#define TT    2048
#define HH    8
#define RDIM  32
#define BB    2

typedef float  f4  __attribute__((ext_vector_type(4)));
typedef int    i4  __attribute__((ext_vector_type(4)));
typedef uint   u2  __attribute__((ext_vector_type(2)));
typedef short  s8v __attribute__((ext_vector_type(8)));   // 8 x bf16 bits (4 VGPR)

// round-to-nearest f32 -> bf16 bits
__device__ __forceinline__ uint rnd16(float x) {
    return (__float_as_uint(x) + 0x8000u) >> 16;
}

// ---------------------------------------------------------------------------
// Kernel 1: fused projection GEMM.  x[4096][1024] @ (Wq|Wk)[1024][256]
// Outputs BOTH projections as bf16 in natural [B,T,H,RD] layout
// ( = [4096][256] bf16 ): sqb (from Wq) and skb (from Wk).
// ---------------------------------------------------------------------------
__global__ __launch_bounds__(256) void proj_gemm(
    const float* __restrict__ x,
    const float* __restrict__ Wq,
    const float* __restrict__ Wk,
    ushort* __restrict__ sqb,
    ushort* __restrict__ skb)
{
    constexpr int BK = 32;
    constexpr int LDA = 68;
    constexpr int LDB = 68;
    __shared__ float As[BK][LDA];   // transposed: As[k][m]
    __shared__ float Bs[BK][LDB];   // Bs[k][n]

    const int m0 = blockIdx.x * 64;
    const int n0 = blockIdx.y * 64;
    const float* W = (n0 < 256) ? Wq : Wk;
    const int nloc = n0 & 255;

    const int tid = threadIdx.x;
    const int tx = tid & 15;            // 16 col groups of 4
    const int ty = tid >> 4;            // 16 row groups of 4

    float acc[4][4] = {};

    for (int k0 = 0; k0 < 1024; k0 += BK) {
        #pragma unroll
        for (int l = 0; l < 2; ++l) {
            int vid = tid + l * 256;
            int row = vid >> 3;         // 0..63
            int cc  = vid & 7;          // k-chunk of 4
            f4 v = *(const f4*)&x[(size_t)(m0 + row) * 1024 + k0 + cc * 4];
            As[cc * 4 + 0][row] = v.x;
            As[cc * 4 + 1][row] = v.y;
            As[cc * 4 + 2][row] = v.z;
            As[cc * 4 + 3][row] = v.w;
        }
        #pragma unroll
        for (int l = 0; l < 2; ++l) {
            int vid = tid + l * 256;
            int kr = vid >> 4;          // 0..31
            int c4 = vid & 15;          // 0..15
            f4 v = *(const f4*)&W[(size_t)(k0 + kr) * 256 + nloc + c4 * 4];
            *(f4*)&Bs[kr][c4 * 4] = v;
        }
        __syncthreads();

        #pragma unroll
        for (int k = 0; k < BK; ++k) {
            const f4 a4 = *(const f4*)&As[k][ty * 4];
            const f4 b4 = *(const f4*)&Bs[k][tx * 4];
            float a[4] = {a4.x, a4.y, a4.z, a4.w};
            float bb[4] = {b4.x, b4.y, b4.z, b4.w};
            #pragma unroll
            for (int r = 0; r < 4; ++r)
                #pragma unroll
                for (int c = 0; c < 4; ++c)
                    acc[r][c] = fmaf(a[r], bb[c], acc[r][c]);
        }
        __syncthreads();
    }

    #pragma unroll
    for (int rr = 0; rr < 4; ++rr) {
        int m = m0 + ty * 4 + rr;
        u2 pk;
        pk.x = (rnd16(acc[rr][1]) << 16) | rnd16(acc[rr][0]);
        pk.y = (rnd16(acc[rr][3]) << 16) | rnd16(acc[rr][2]);
        int nn = n0 + tx * 4;
        if (nn < 256) {
            *(u2*)&sqb[(size_t)m * 256 + nn] = pk;
        } else {
            *(u2*)&skb[(size_t)m * 256 + (nn - 256)] = pk;
        }
    }
}

// ---------------------------------------------------------------------------
// Kernel 2: MFMA scores + mask + gumbel + softmax, SWAPPED operands.
// mfma(A=sk_tile, B=sq_tile) -> D[m=j][n=i] = scores[i][j]; with the gfx950
// C layout (col=lane&15 -> i, row=(lane>>4)*4+reg -> j) each lane owns ONE
// output row i and 4 CONSECUTIVE columns j -> gumbel/mask/out are all f4/i4
// (16B/lane). sq fragment is strip-invariant (loaded once). exp values are
// packed 2xbf16 in p[16] (static indexing), so pass 2 is unpack+scale+store
// (no recompute, no re-loads).
// One 512-thr block per balanced strip-pair (strips s and 127-s of one bh,
// 16 rows each) -> uniform 129 live 16x16 tiles per block; wave w takes
// tiles {w, w+8, ...}.
// ---------------------------------------------------------------------------
__global__ __launch_bounds__(512) void score_mfma(
    const ushort* __restrict__ sqb,     // [4096][256] bf16 bits
    const ushort* __restrict__ skb,     // [4096][256] bf16 bits
    const float*  __restrict__ gumbel,  // [B,H,T,T] f32
    const int*    __restrict__ mask,    // [H,T,T] int32 bool
    float* __restrict__ out)            // [B,H,T,T] f32
{
    const int tid = threadIdx.x;
    const int l   = tid & 63;
    const int w   = __builtin_amdgcn_readfirstlane(tid) >> 6;  // wave id 0..7
    const int bh  = blockIdx.x & 15;
    const int sp  = blockIdx.x >> 4;     // 0..63
    const int h   = bh & (HH - 1);
    const int b   = bh >> 3;
    const int cl  = l & 15;              // C col -> output row i offset
    const int g4  = l >> 4;              // 0..3  -> j sub-block
    const float RS = 0.17677669529663687f;  // 1/sqrt(RD)

    __shared__ float sums_lds[8][16];

    const ushort* sqbase = sqb + ((size_t)b * TT) * 256 + h * RDIM + g4 * 8;
    const ushort* skbase = skb + ((size_t)b * TT) * 256 + h * RDIM + g4 * 8;
    const float*  gb = gumbel + (size_t)bh * TT * TT;
    const int*    mb = mask + (size_t)h * TT * TT;
    float*        ob = out + (size_t)bh * TT * TT;

    #pragma unroll 1
    for (int half = 0; half < 2; ++half) {
        const int s      = half ? (127 - sp) : sp;
        const int i0     = s * 16;
        const int ntiles = s + 1;        // live 16-col tiles (incl. diagonal)
        const int zstart = ntiles * 16;
        const int i      = i0 + cl;      // this lane's output row

        // B fragment (sq row i): strip-invariant
        s8v bfrag = *(const s8v*)(sqbase + (size_t)i * 256);

        const float* grow = gb + (size_t)i * TT;
        const int*   mrow = mb + (size_t)i * TT;
        float*       orow = ob + (size_t)i * TT;

        // ---- pass 1: MFMA + exp, pack bf16, accumulate row sum ----
        float sum = 0.f;
        u2 p[16];
        #pragma unroll
        for (int it = 0; it < 16; ++it) {
            const int jt = w + it * 8;   // wave-uniform tile index
            if (jt < ntiles) {
                // A fragment (sk row j): row = jt*16 + (lane&15)
                s8v afrag = *(const s8v*)(skbase + (size_t)(jt * 16 + cl) * 256);
                f4 z = {0.f, 0.f, 0.f, 0.f};
                f4 c = __builtin_amdgcn_mfma_f32_16x16x32_bf16(
                           afrag, bfrag, z, 0, 0, 0);
                const int jb = jt * 16 + g4 * 4;   // 4 consecutive cols
                f4 gv = *(const f4*)&grow[jb];
                i4 mv = *(const i4*)&mrow[jb];
                float e0 = (jb + 0 > i || mv.x) ? 0.f : __expf(fmaf(c[0], RS, gv.x));
                float e1 = (jb + 1 > i || mv.y) ? 0.f : __expf(fmaf(c[1], RS, gv.y));
                float e2 = (jb + 2 > i || mv.z) ? 0.f : __expf(fmaf(c[2], RS, gv.z));
                float e3 = (jb + 3 > i || mv.w) ? 0.f : __expf(fmaf(c[3], RS, gv.w));
                sum += (e0 + e1) + (e2 + e3);
                p[it].x = (rnd16(e1) << 16) | rnd16(e0);
                p[it].y = (rnd16(e3) << 16) | rnd16(e2);
            }
        }

        // ---- row-sum reduce: across g4 groups, then across waves ----
        sum += __shfl_xor(sum, 16);
        sum += __shfl_xor(sum, 32);
        if (l < 16) sums_lds[w][l] = sum;
        __syncthreads();
        float t = 0.f;
        #pragma unroll
        for (int ww = 0; ww < 8; ++ww) t += sums_lds[ww][cl];
        const float rinv = 1.0f / t;     // diagonal always live -> t > 0
        __syncthreads();                 // LDS reused by next half

        // ---- pass 2: unpack + scale + store ----
        #pragma unroll
        for (int it = 0; it < 16; ++it) {
            const int jt = w + it * 8;
            if (jt < ntiles) {
                const int jb = jt * 16 + g4 * 4;
                f4 v;
                v.x = __uint_as_float(p[it].x << 16) * rinv;
                v.y = __uint_as_float(p[it].x & 0xffff0000u) * rinv;
                v.z = __uint_as_float(p[it].y << 16) * rinv;
                v.w = __uint_as_float(p[it].y & 0xffff0000u) * rinv;
                *(f4*)&orow[jb] = v;
            }
        }

        // ---- zero-fill cols beyond the causal frontier ----
        for (int r = 0; r < 16; ++r) {
            for (int cz = zstart + tid * 4; cz < TT; cz += 512 * 4) {
                f4 zz = {0.f, 0.f, 0.f, 0.f};
                *(f4*)&ob[(size_t)(i0 + r) * TT + cz] = zz;
            }
        }
    }
}

extern "C" void kernel_launch(void* const* d_in, const int* in_sizes, int n_in,
                              void* d_out, int out_size, void* d_ws, size_t ws_size,
                              hipStream_t stream) {
    const float* x      = (const float*)d_in[0];
    const int*   bmask  = (const int*)d_in[1];   // bool -> int32 per harness
    const float* gumbel = (const float*)d_in[2];
    const float* Wq     = (const float*)d_in[3];
    const float* Wk     = (const float*)d_in[4];
    float* out = (float*)d_out;

    ushort* sqb = (ushort*)d_ws;                       // 4096*256 bf16 = 2 MB
    ushort* skb = sqb + (size_t)4096 * 256;            // 2 MB

    proj_gemm<<<dim3(64, 8), 256, 0, stream>>>(x, Wq, Wk, sqb, skb);

    // 16 bh x 64 balanced strip-pairs, 512 thr (8 waves) each
    score_mfma<<<1024, 512, 0, stream>>>(sqb, skb, gumbel, bmask, out);
}

// Round 9
// 190.693 us; speedup vs baseline: 6.5644x; 1.1165x over previous
//
#include <hip/hip_runtime.h>
#include <hip/hip_bf16.h>
#include <math.h>

// Problem constants
#define TT    2048
#define HH    8
#define RDIM  32
#define BB    2

typedef float  f4  __attribute__((ext_vector_type(4)));
typedef int    i4  __attribute__((ext_vector_type(4)));
typedef uint   u2  __attribute__((ext_vector_type(2)));
typedef short  s8v __attribute__((ext_vector_type(8)));   // 8 x bf16 bits (4 VGPR)

// round-to-nearest f32 -> bf16 bits
__device__ __forceinline__ uint rnd16(float x) {
    return (__float_as_uint(x) + 0x8000u) >> 16;
}

// ---------------------------------------------------------------------------
// Kernel 1: fused projection GEMM.  x[4096][1024] @ (Wq|Wk)[1024][256]
// Outputs BOTH projections as bf16 in natural [B,T,H,RD] layout
// ( = [4096][256] bf16 ): sqb (from Wq) and skb (from Wk).
// ---------------------------------------------------------------------------
__global__ __launch_bounds__(256) void proj_gemm(
    const float* __restrict__ x,
    const float* __restrict__ Wq,
    const float* __restrict__ Wk,
    ushort* __restrict__ sqb,
    ushort* __restrict__ skb)
{
    constexpr int BK = 32;
    constexpr int LDA = 68;
    constexpr int LDB = 68;
    __shared__ float As[BK][LDA];   // transposed: As[k][m]
    __shared__ float Bs[BK][LDB];   // Bs[k][n]

    const int m0 = blockIdx.x * 64;
    const int n0 = blockIdx.y * 64;
    const float* W = (n0 < 256) ? Wq : Wk;
    const int nloc = n0 & 255;

    const int tid = threadIdx.x;
    const int tx = tid & 15;            // 16 col groups of 4
    const int ty = tid >> 4;            // 16 row groups of 4

    float acc[4][4] = {};

    for (int k0 = 0; k0 < 1024; k0 += BK) {
        #pragma unroll
        for (int l = 0; l < 2; ++l) {
            int vid = tid + l * 256;
            int row = vid >> 3;         // 0..63
            int cc  = vid & 7;          // k-chunk of 4
            f4 v = *(const f4*)&x[(size_t)(m0 + row) * 1024 + k0 + cc * 4];
            As[cc * 4 + 0][row] = v.x;
            As[cc * 4 + 1][row] = v.y;
            As[cc * 4 + 2][row] = v.z;
            As[cc * 4 + 3][row] = v.w;
        }
        #pragma unroll
        for (int l = 0; l < 2; ++l) {
            int vid = tid + l * 256;
            int kr = vid >> 4;          // 0..31
            int c4 = vid & 15;          // 0..15
            f4 v = *(const f4*)&W[(size_t)(k0 + kr) * 256 + nloc + c4 * 4];
            *(f4*)&Bs[kr][c4 * 4] = v;
        }
        __syncthreads();

        #pragma unroll
        for (int k = 0; k < BK; ++k) {
            const f4 a4 = *(const f4*)&As[k][ty * 4];
            const f4 b4 = *(const f4*)&Bs[k][tx * 4];
            float a[4] = {a4.x, a4.y, a4.z, a4.w};
            float bb[4] = {b4.x, b4.y, b4.z, b4.w};
            #pragma unroll
            for (int r = 0; r < 4; ++r)
                #pragma unroll
                for (int c = 0; c < 4; ++c)
                    acc[r][c] = fmaf(a[r], bb[c], acc[r][c]);
        }
        __syncthreads();
    }

    #pragma unroll
    for (int rr = 0; rr < 4; ++rr) {
        int m = m0 + ty * 4 + rr;
        u2 pk;
        pk.x = (rnd16(acc[rr][1]) << 16) | rnd16(acc[rr][0]);
        pk.y = (rnd16(acc[rr][3]) << 16) | rnd16(acc[rr][2]);
        int nn = n0 + tx * 4;
        if (nn < 256) {
            *(u2*)&sqb[(size_t)m * 256 + nn] = pk;
        } else {
            *(u2*)&skb[(size_t)m * 256 + (nn - 256)] = pk;
        }
    }
}

// ---------------------------------------------------------------------------
// Kernel 2: MFMA scores + mask + gumbel + softmax (swapped operands).
// mfma(A=sk_tile, B=sq_tile): C col=lane&15 -> output row i, C rows -> 4
// consecutive cols j. Each wave now processes TWO ADJACENT tiles per
// unrolled iteration (jt = 2w + 16*it, jt+1): per output row a wave covers
// 32 consecutive cols -> its paired f4 loads/stores consume FULL 128B cache
// lines, and the two tiles form independent MFMA/load chains (2x ILP).
// exp packed 2xbf16 in p[8][2] (static idx); pass 2 = unpack+scale+store.
// Stores are nontemporal (write-once). One 512-thr block per balanced
// strip-pair (s, 127-s): uniform 129 live tiles/block.
// ---------------------------------------------------------------------------
__global__ __launch_bounds__(512) void score_mfma(
    const ushort* __restrict__ sqb,     // [4096][256] bf16 bits
    const ushort* __restrict__ skb,     // [4096][256] bf16 bits
    const float*  __restrict__ gumbel,  // [B,H,T,T] f32
    const int*    __restrict__ mask,    // [H,T,T] int32 bool
    float* __restrict__ out)            // [B,H,T,T] f32
{
    const int tid = threadIdx.x;
    const int l   = tid & 63;
    const int w   = __builtin_amdgcn_readfirstlane(tid) >> 6;  // wave id 0..7
    const int bh  = blockIdx.x & 15;
    const int sp  = blockIdx.x >> 4;     // 0..63
    const int h   = bh & (HH - 1);
    const int b   = bh >> 3;
    const int cl  = l & 15;              // C col -> output row i offset
    const int g4  = l >> 4;              // 0..3  -> j sub-block
    const float RS = 0.17677669529663687f;  // 1/sqrt(RD)

    __shared__ float sums_lds[8][16];

    const ushort* sqbase = sqb + ((size_t)b * TT) * 256 + h * RDIM + g4 * 8;
    const ushort* skbase = skb + ((size_t)b * TT) * 256 + h * RDIM + g4 * 8;
    const float*  gb = gumbel + (size_t)bh * TT * TT;
    const int*    mb = mask + (size_t)h * TT * TT;
    float*        ob = out + (size_t)bh * TT * TT;

    #pragma unroll 1
    for (int half = 0; half < 2; ++half) {
        const int s      = half ? (127 - sp) : sp;
        const int i0     = s * 16;
        const int ntiles = s + 1;        // live 16-col tiles (max 128)
        const int zstart = ntiles * 16;
        const int i      = i0 + cl;      // this lane's output row

        // B fragment (sq row i): strip-invariant
        s8v bfrag = *(const s8v*)(sqbase + (size_t)i * 256);

        const float* grow = gb + (size_t)i * TT;
        const int*   mrow = mb + (size_t)i * TT;
        float*       orow = ob + (size_t)i * TT;

        // ---- pass 1: MFMA + exp, pack bf16, accumulate row sum ----
        float sum = 0.f;
        u2 p[8][2];
        #pragma unroll
        for (int it = 0; it < 8; ++it) {
            const int jt0 = 2 * w + it * 16;   // wave-uniform pair base
            #pragma unroll
            for (int u = 0; u < 2; ++u) {
                const int jt = jt0 + u;
                if (jt < ntiles) {
                    // A fragment (sk row j): row = jt*16 + (lane&15)
                    s8v afrag = *(const s8v*)(skbase + (size_t)(jt * 16 + cl) * 256);
                    f4 z = {0.f, 0.f, 0.f, 0.f};
                    f4 c = __builtin_amdgcn_mfma_f32_16x16x32_bf16(
                               afrag, bfrag, z, 0, 0, 0);
                    const int jb = jt * 16 + g4 * 4;   // 4 consecutive cols
                    f4 gv = *(const f4*)&grow[jb];
                    i4 mv = *(const i4*)&mrow[jb];
                    float e0 = (jb + 0 > i || mv.x) ? 0.f : __expf(fmaf(c[0], RS, gv.x));
                    float e1 = (jb + 1 > i || mv.y) ? 0.f : __expf(fmaf(c[1], RS, gv.y));
                    float e2 = (jb + 2 > i || mv.z) ? 0.f : __expf(fmaf(c[2], RS, gv.z));
                    float e3 = (jb + 3 > i || mv.w) ? 0.f : __expf(fmaf(c[3], RS, gv.w));
                    sum += (e0 + e1) + (e2 + e3);
                    p[it][u].x = (rnd16(e1) << 16) | rnd16(e0);
                    p[it][u].y = (rnd16(e3) << 16) | rnd16(e2);
                }
            }
        }

        // ---- row-sum reduce: across g4 groups, then across waves ----
        sum += __shfl_xor(sum, 16);
        sum += __shfl_xor(sum, 32);
        if (l < 16) sums_lds[w][l] = sum;
        __syncthreads();
        float t = 0.f;
        #pragma unroll
        for (int ww = 0; ww < 8; ++ww) t += sums_lds[ww][cl];
        const float rinv = 1.0f / t;     // diagonal always live -> t > 0
        __syncthreads();                 // LDS reused by next half

        // ---- pass 2: unpack + scale + nontemporal store ----
        #pragma unroll
        for (int it = 0; it < 8; ++it) {
            const int jt0 = 2 * w + it * 16;
            #pragma unroll
            for (int u = 0; u < 2; ++u) {
                const int jt = jt0 + u;
                if (jt < ntiles) {
                    const int jb = jt * 16 + g4 * 4;
                    f4 v;
                    v.x = __uint_as_float(p[it][u].x << 16) * rinv;
                    v.y = __uint_as_float(p[it][u].x & 0xffff0000u) * rinv;
                    v.z = __uint_as_float(p[it][u].y << 16) * rinv;
                    v.w = __uint_as_float(p[it][u].y & 0xffff0000u) * rinv;
                    __builtin_nontemporal_store(v, (f4*)&orow[jb]);
                }
            }
        }

        // ---- zero-fill cols beyond the causal frontier ----
        for (int r = 0; r < 16; ++r) {
            for (int cz = zstart + tid * 4; cz < TT; cz += 512 * 4) {
                f4 zz = {0.f, 0.f, 0.f, 0.f};
                __builtin_nontemporal_store(zz, (f4*)&ob[(size_t)(i0 + r) * TT + cz]);
            }
        }
    }
}

extern "C" void kernel_launch(void* const* d_in, const int* in_sizes, int n_in,
                              void* d_out, int out_size, void* d_ws, size_t ws_size,
                              hipStream_t stream) {
    const float* x      = (const float*)d_in[0];
    const int*   bmask  = (const int*)d_in[1];   // bool -> int32 per harness
    const float* gumbel = (const float*)d_in[2];
    const float* Wq     = (const float*)d_in[3];
    const float* Wk     = (const float*)d_in[4];
    float* out = (float*)d_out;

    ushort* sqb = (ushort*)d_ws;                       // 4096*256 bf16 = 2 MB
    ushort* skb = sqb + (size_t)4096 * 256;            // 2 MB

    proj_gemm<<<dim3(64, 8), 256, 0, stream>>>(x, Wq, Wk, sqb, skb);

    // 16 bh x 64 balanced strip-pairs, 512 thr (8 waves) each
    score_mfma<<<1024, 512, 0, stream>>>(sqb, skb, gumbel, bmask, out);
}

// Round 10
// 187.798 us; speedup vs baseline: 6.6656x; 1.0154x over previous
//
#include <hip/hip_runtime.h>
#include <hip/hip_bf16.h>
#include <math.h>

// Problem constants
#define TT    2048
#define HH    8
#define RDIM  32
#define BB    2

typedef float  f4  __attribute__((ext_vector_type(4)));
typedef int    i4  __attribute__((ext_vector_type(4)));
typedef uint   u2  __attribute__((ext_vector_type(2)));
typedef uint   u4  __attribute__((ext_vector_type(4)));
typedef short  s8v __attribute__((ext_vector_type(8)));   // 8 x bf16 bits (4 VGPR)

// round-to-nearest f32 -> bf16 bits
__device__ __forceinline__ uint rnd16(float x) {
    return (__float_as_uint(x) + 0x8000u) >> 16;
}

union v8cast { u4 u; s8v s; };

// ---------------------------------------------------------------------------
// Kernel 0: Wt prep — transpose (Wq|Wk)[1024][256+256] f32 -> Wt[512][1024]
// bf16 (Wt[n][k] = W[k][n]). LDS-tiled 64x64. 1 MB output, L2-resident for
// proj_mfma.
// ---------------------------------------------------------------------------
__global__ __launch_bounds__(256) void wt_prep(
    const float* __restrict__ Wq,
    const float* __restrict__ Wk,
    ushort* __restrict__ Wt)
{
    __shared__ float T[64][68];
    const int k0 = blockIdx.x * 64;
    const int n0 = blockIdx.y * 64;
    const float* W = (n0 < 256) ? Wq : Wk;
    const int nloc = n0 & 255;
    const int tid = threadIdx.x;

    // load 64k x 64n, store transposed into LDS
    #pragma unroll
    for (int r = 0; r < 4; ++r) {
        int kl  = (tid >> 4) + r * 16;
        int nl4 = (tid & 15) * 4;
        f4 v = *(const f4*)&W[(size_t)(k0 + kl) * 256 + nloc + nl4];
        T[nl4 + 0][kl] = v.x;
        T[nl4 + 1][kl] = v.y;
        T[nl4 + 2][kl] = v.z;
        T[nl4 + 3][kl] = v.w;
    }
    __syncthreads();

    // write rows of Wt: 16 bf16 (32B) per thread
    const int nl = tid >> 2;
    const int kq = (tid & 3) * 16;
    u4 o0, o1;
    #pragma unroll
    for (int j = 0; j < 4; ++j) {
        uint lo = rnd16(T[nl][kq + 2 * j]);
        uint hi = rnd16(T[nl][kq + 2 * j + 1]);
        ((uint*)&o0)[j] = (hi << 16) | lo;
    }
    #pragma unroll
    for (int j = 0; j < 4; ++j) {
        uint lo = rnd16(T[nl][kq + 8 + 2 * j]);
        uint hi = rnd16(T[nl][kq + 8 + 2 * j + 1]);
        ((uint*)&o1)[j] = (hi << 16) | lo;
    }
    ushort* dst = Wt + (size_t)(n0 + nl) * 1024 + k0 + kq;
    *(u4*)dst = o0;
    *(u4*)(dst + 8) = o1;
}

// ---------------------------------------------------------------------------
// Kernel 1: MFMA projection.  sq/sk[m][n] = sum_k x[m][k] * Wt[n][k]
// mfma(A=Wt_tile, B=x_tile): A row (lane&15) -> n, B col (lane&15) -> m,
// D: lane owns col m = lane&15, rows n = (lane>>4)*4+reg (4 consecutive n).
// Each wave: 16 m-rows x 64 n-cols, K-loop 32 steps, 4 MFMA/step.
// x loaded f32 (32B/lane/step) and converted to bf16 in-register.
// Epilogue: 8B u2 stores (4 bf16) per n-subtile.
// ---------------------------------------------------------------------------
__global__ __launch_bounds__(256) void proj_mfma(
    const float* __restrict__ x,       // [4096][1024] f32
    const ushort* __restrict__ Wt,     // [512][1024] bf16 bits
    ushort* __restrict__ sqb,          // [4096][256] bf16 bits
    ushort* __restrict__ skb)          // [4096][256] bf16 bits
{
    const int tid = threadIdx.x;
    const int l   = tid & 63;
    const int w   = __builtin_amdgcn_readfirstlane(tid) >> 6;  // 0..3
    const int cl  = l & 15;
    const int g4  = l >> 4;
    const int m0  = (blockIdx.x * 4 + w) * 16;   // m-tile
    const int n0  = blockIdx.y * 64;             // n-block (64 wide)

    f4 acc0 = {0,0,0,0}, acc1 = {0,0,0,0}, acc2 = {0,0,0,0}, acc3 = {0,0,0,0};

    const float*  xrow = x + (size_t)(m0 + cl) * 1024;
    const ushort* wbase = Wt + (size_t)(n0 + cl) * 1024;

    for (int ks = 0; ks < 32; ++ks) {
        const int k = ks * 32 + g4 * 8;
        // B fragment: x row m0+cl, 8 f32 -> 8 bf16
        f4 xa = *(const f4*)&xrow[k];
        f4 xb2 = *(const f4*)&xrow[k + 4];
        v8cast bf;
        ((uint*)&bf.u)[0] = (rnd16(xa.y) << 16) | rnd16(xa.x);
        ((uint*)&bf.u)[1] = (rnd16(xa.w) << 16) | rnd16(xa.z);
        ((uint*)&bf.u)[2] = (rnd16(xb2.y) << 16) | rnd16(xb2.x);
        ((uint*)&bf.u)[3] = (rnd16(xb2.w) << 16) | rnd16(xb2.z);
        // A fragments: Wt rows n0+t*16+cl (16B contiguous)
        s8v a0 = *(const s8v*)(wbase + 0 * 16 * 1024 + k);
        s8v a1 = *(const s8v*)(wbase + 1 * 16 * 1024 + k);
        s8v a2 = *(const s8v*)(wbase + 2 * 16 * 1024 + k);
        s8v a3 = *(const s8v*)(wbase + 3 * 16 * 1024 + k);
        acc0 = __builtin_amdgcn_mfma_f32_16x16x32_bf16(a0, bf.s, acc0, 0, 0, 0);
        acc1 = __builtin_amdgcn_mfma_f32_16x16x32_bf16(a1, bf.s, acc1, 0, 0, 0);
        acc2 = __builtin_amdgcn_mfma_f32_16x16x32_bf16(a2, bf.s, acc2, 0, 0, 0);
        acc3 = __builtin_amdgcn_mfma_f32_16x16x32_bf16(a3, bf.s, acc3, 0, 0, 0);
    }

    // epilogue: lane owns m = m0+cl, 4 consecutive n per subtile
    const int m = m0 + cl;
    const int nbase = n0 + g4 * 4;
    ushort* obase = (n0 < 256) ? (sqb + (size_t)m * 256 + nbase)
                               : (skb + (size_t)m * 256 + (nbase - 256));
    f4 accs[4] = {acc0, acc1, acc2, acc3};
    #pragma unroll
    for (int t = 0; t < 4; ++t) {
        u2 pk;
        pk.x = (rnd16(accs[t][1]) << 16) | rnd16(accs[t][0]);
        pk.y = (rnd16(accs[t][3]) << 16) | rnd16(accs[t][2]);
        *(u2*)(obase + t * 16) = pk;
    }
}

// ---------------------------------------------------------------------------
// Kernel 2: MFMA scores + mask + gumbel + softmax (swapped operands).
// mfma(A=sk_tile, B=sq_tile): C col=lane&15 -> output row i, C rows -> 4
// consecutive cols j. Each wave processes TWO ADJACENT tiles per unrolled
// iteration (jt = 2w + 16*it, +1): per output row a wave covers 32
// consecutive cols -> paired f4 loads/stores consume full 128B lines, two
// independent MFMA/load chains. exp packed 2xbf16 in p[8][2] (static idx);
// pass 2 = unpack+scale+store (plain cached stores — NT half-line stores
// caused HBM RMW, +58MB WRITE, R9 regression).
// One 512-thr block per balanced strip-pair (s, 127-s): 129 tiles/block.
// ---------------------------------------------------------------------------
__global__ __launch_bounds__(512) void score_mfma(
    const ushort* __restrict__ sqb,     // [4096][256] bf16 bits
    const ushort* __restrict__ skb,     // [4096][256] bf16 bits
    const float*  __restrict__ gumbel,  // [B,H,T,T] f32
    const int*    __restrict__ mask,    // [H,T,T] int32 bool
    float* __restrict__ out)            // [B,H,T,T] f32
{
    const int tid = threadIdx.x;
    const int l   = tid & 63;
    const int w   = __builtin_amdgcn_readfirstlane(tid) >> 6;  // wave id 0..7
    const int bh  = blockIdx.x & 15;
    const int sp  = blockIdx.x >> 4;     // 0..63
    const int h   = bh & (HH - 1);
    const int b   = bh >> 3;
    const int cl  = l & 15;              // C col -> output row i offset
    const int g4  = l >> 4;              // 0..3  -> j sub-block
    const float RS = 0.17677669529663687f;  // 1/sqrt(RD)

    __shared__ float sums_lds[8][16];

    const ushort* sqbase = sqb + ((size_t)b * TT) * 256 + h * RDIM + g4 * 8;
    const ushort* skbase = skb + ((size_t)b * TT) * 256 + h * RDIM + g4 * 8;
    const float*  gb = gumbel + (size_t)bh * TT * TT;
    const int*    mb = mask + (size_t)h * TT * TT;
    float*        ob = out + (size_t)bh * TT * TT;

    #pragma unroll 1
    for (int half = 0; half < 2; ++half) {
        const int s      = half ? (127 - sp) : sp;
        const int i0     = s * 16;
        const int ntiles = s + 1;        // live 16-col tiles (max 128)
        const int zstart = ntiles * 16;
        const int i      = i0 + cl;      // this lane's output row

        // B fragment (sq row i): strip-invariant
        s8v bfrag = *(const s8v*)(sqbase + (size_t)i * 256);

        const float* grow = gb + (size_t)i * TT;
        const int*   mrow = mb + (size_t)i * TT;
        float*       orow = ob + (size_t)i * TT;

        // ---- pass 1: MFMA + exp, pack bf16, accumulate row sum ----
        float sum = 0.f;
        u2 p[8][2];
        #pragma unroll
        for (int it = 0; it < 8; ++it) {
            const int jt0 = 2 * w + it * 16;   // wave-uniform pair base
            #pragma unroll
            for (int u = 0; u < 2; ++u) {
                const int jt = jt0 + u;
                if (jt < ntiles) {
                    // A fragment (sk row j): row = jt*16 + (lane&15)
                    s8v afrag = *(const s8v*)(skbase + (size_t)(jt * 16 + cl) * 256);
                    f4 z = {0.f, 0.f, 0.f, 0.f};
                    f4 c = __builtin_amdgcn_mfma_f32_16x16x32_bf16(
                               afrag, bfrag, z, 0, 0, 0);
                    const int jb = jt * 16 + g4 * 4;   // 4 consecutive cols
                    f4 gv = *(const f4*)&grow[jb];
                    i4 mv = *(const i4*)&mrow[jb];
                    float e0 = (jb + 0 > i || mv.x) ? 0.f : __expf(fmaf(c[0], RS, gv.x));
                    float e1 = (jb + 1 > i || mv.y) ? 0.f : __expf(fmaf(c[1], RS, gv.y));
                    float e2 = (jb + 2 > i || mv.z) ? 0.f : __expf(fmaf(c[2], RS, gv.z));
                    float e3 = (jb + 3 > i || mv.w) ? 0.f : __expf(fmaf(c[3], RS, gv.w));
                    sum += (e0 + e1) + (e2 + e3);
                    p[it][u].x = (rnd16(e1) << 16) | rnd16(e0);
                    p[it][u].y = (rnd16(e3) << 16) | rnd16(e2);
                }
            }
        }

        // ---- row-sum reduce: across g4 groups, then across waves ----
        sum += __shfl_xor(sum, 16);
        sum += __shfl_xor(sum, 32);
        if (l < 16) sums_lds[w][l] = sum;
        __syncthreads();
        float t = 0.f;
        #pragma unroll
        for (int ww = 0; ww < 8; ++ww) t += sums_lds[ww][cl];
        const float rinv = 1.0f / t;     // diagonal always live -> t > 0
        __syncthreads();                 // LDS reused by next half

        // ---- pass 2: unpack + scale + store (plain cached stores) ----
        #pragma unroll
        for (int it = 0; it < 8; ++it) {
            const int jt0 = 2 * w + it * 16;
            #pragma unroll
            for (int u = 0; u < 2; ++u) {
                const int jt = jt0 + u;
                if (jt < ntiles) {
                    const int jb = jt * 16 + g4 * 4;
                    f4 v;
                    v.x = __uint_as_float(p[it][u].x << 16) * rinv;
                    v.y = __uint_as_float(p[it][u].x & 0xffff0000u) * rinv;
                    v.z = __uint_as_float(p[it][u].y << 16) * rinv;
                    v.w = __uint_as_float(p[it][u].y & 0xffff0000u) * rinv;
                    *(f4*)&orow[jb] = v;
                }
            }
        }

        // ---- zero-fill cols beyond the causal frontier ----
        for (int r = 0; r < 16; ++r) {
            for (int cz = zstart + tid * 4; cz < TT; cz += 512 * 4) {
                f4 zz = {0.f, 0.f, 0.f, 0.f};
                *(f4*)&ob[(size_t)(i0 + r) * TT + cz] = zz;
            }
        }
    }
}

extern "C" void kernel_launch(void* const* d_in, const int* in_sizes, int n_in,
                              void* d_out, int out_size, void* d_ws, size_t ws_size,
                              hipStream_t stream) {
    const float* x      = (const float*)d_in[0];
    const int*   bmask  = (const int*)d_in[1];   // bool -> int32 per harness
    const float* gumbel = (const float*)d_in[2];
    const float* Wq     = (const float*)d_in[3];
    const float* Wk     = (const float*)d_in[4];
    float* out = (float*)d_out;

    ushort* sqb = (ushort*)d_ws;                       // 4096*256 bf16 = 2 MB
    ushort* skb = sqb + (size_t)4096 * 256;            // 2 MB
    ushort* Wt  = skb + (size_t)4096 * 256;            // 512*1024 bf16 = 1 MB

    // W transpose + bf16 (tiny, Wt is L2-resident afterwards)
    wt_prep<<<dim3(16, 8), 256, 0, stream>>>(Wq, Wk, Wt);

    // MFMA projection: 256 m-tiles x 8 n-blocks, 4 waves/block
    proj_mfma<<<dim3(64, 8), 256, 0, stream>>>(x, Wt, sqb, skb);

    // 16 bh x 64 balanced strip-pairs, 512 thr (8 waves) each
    score_mfma<<<1024, 512, 0, stream>>>(sqb, skb, gumbel, bmask, out);
}